// Round 2
// baseline (1012.057 us; speedup 1.0000x reference)
//
#include <hip/hip_runtime.h>

#define NH 8
#define HD 64
#define NB 64
#define MAXS 512
#define QROWS 256
#define KVB 64
#define QKVSTRIDE (3 * NH * HD)   // 1536 floats per token

__global__ __launch_bounds__(256, 2)
void varlen_attn_fp32(const float* __restrict__ qkv, const int* __restrict__ cu,
                      float* __restrict__ out) {
  const int bh = blockIdx.x;
  const int b = bh >> 3;          // / NH
  const int h = bh & 7;           // % NH
  const int start = cu[b];
  const int end = cu[b + 1];
  const int len = end - start;
  if ((int)(blockIdx.y * QROWS) >= len) return;   // block-uniform early exit
  const int r = blockIdx.y * QROWS + threadIdx.x;
  const bool active = r < len;

  __shared__ float Ks[KVB][HD];
  __shared__ float Vs[KVB][HD];

  // load q row (pre-scaled by 1/sqrt(64) = 0.125)
  float q[HD];
  float o[HD];
  const int tq = start + (active ? r : 0);
  const float* qrow = qkv + (size_t)tq * QKVSTRIDE + h * HD;
#pragma unroll
  for (int d = 0; d < HD; d += 4) {
    float4 t = *(const float4*)(qrow + d);
    q[d + 0] = t.x * 0.125f;
    q[d + 1] = t.y * 0.125f;
    q[d + 2] = t.z * 0.125f;
    q[d + 3] = t.w * 0.125f;
  }
#pragma unroll
  for (int d = 0; d < HD; ++d) o[d] = 0.f;

  float m = -1e30f;
  float l = 0.f;

  for (int kv0 = 0; kv0 < len; kv0 += KVB) {
    const int nk = min(KVB, len - kv0);
    __syncthreads();
    // stage K and V tiles: KVB*HD = 4096 floats each; 256 threads * 4 float4
#pragma unroll
    for (int it = 0; it < (KVB * HD) / (256 * 4); ++it) {
      const int i = (it * 256 + threadIdx.x) * 4;  // flat float index
      const int key = i >> 6;                      // / HD
      const int d = i & 63;                        // % HD
      if (key < nk) {
        const float* base = qkv + (size_t)(start + kv0 + key) * QKVSTRIDE + h * HD;
        *(float4*)&Ks[key][d] = *(const float4*)(base + NH * HD + d);      // K  (+d: the R1 bug)
        *(float4*)&Vs[key][d] = *(const float4*)(base + 2 * NH * HD + d);  // V  (+d: the R1 bug)
      }
    }
    __syncthreads();

    if (active) {
      for (int j = 0; j < nk; ++j) {
        // dot(q, K[j]) with 4 partial sums to break the FMA dependence chain
        float s0 = 0.f, s1 = 0.f, s2 = 0.f, s3 = 0.f;
#pragma unroll
        for (int d = 0; d < HD; d += 4) {
          s0 += q[d + 0] * Ks[j][d + 0];
          s1 += q[d + 1] * Ks[j][d + 1];
          s2 += q[d + 2] * Ks[j][d + 2];
          s3 += q[d + 3] * Ks[j][d + 3];
        }
        const float s = (s0 + s1) + (s2 + s3);
        const float mn = fmaxf(m, s);
        const float c = __expf(m - mn);
        const float p = __expf(s - mn);
        l = l * c + p;
#pragma unroll
        for (int d = 0; d < HD; ++d) o[d] = o[d] * c + p * Vs[j][d];
        m = mn;
      }
    }
  }

  if (active) {
    const float inv = 1.f / l;
    float* orow = out + (size_t)(start + r) * (NH * HD) + h * HD;
#pragma unroll
    for (int d = 0; d < HD; d += 4) {
      float4 t;
      t.x = o[d + 0] * inv;
      t.y = o[d + 1] * inv;
      t.z = o[d + 2] * inv;
      t.w = o[d + 3] * inv;
      *(float4*)(orow + d) = t;
    }
  }
}

extern "C" void kernel_launch(void* const* d_in, const int* in_sizes, int n_in,
                              void* d_out, int out_size, void* d_ws, size_t ws_size,
                              hipStream_t stream) {
  const float* qkv = (const float*)d_in[0];
  const int* cu = (const int*)d_in[1];
  float* out = (float*)d_out;
  dim3 grid(NB * NH, MAXS / QROWS);   // (512, 2); B=64 is a problem constant
  varlen_attn_fp32<<<grid, 256, 0, stream>>>(qkv, cu, out);
}

// Round 3
// 98.014 us; speedup vs baseline: 10.3256x; 10.3256x over previous
//
#include <hip/hip_runtime.h>
#include <stdint.h>

#define NH 8
#define HD 64
#define MAXS 512
#define QT 64          // q rows per block (16 per wave)
#define KVB 64         // keys per kv tile
#define TOKS 1536      // 3*NH*HD floats per token
#define OUTS 512       // NH*HD floats per token

typedef __attribute__((ext_vector_type(8))) short bf16x8;
typedef __attribute__((ext_vector_type(4))) short bf16x4;
typedef __attribute__((ext_vector_type(4))) float f32x4;

// f32 -> bf16 bits, round-to-nearest-even
__device__ __forceinline__ short f2bf(float f) {
  uint32_t u = __float_as_uint(f);
  u += 0x7fffu + ((u >> 16) & 1u);
  return (short)(u >> 16);
}

// XOR swizzle: idx is short-index (row*64 + col) into a [R][64]-bf16 array
// (row stride = 128 B). Flips 16B-slot bits so fragment reads (16 rows x 4
// k-subranges) and staging writes spread across all 32 banks.
__device__ __forceinline__ int swz(int row, int idx) {
  return idx ^ ((((row & 7) ^ ((row >> 3) & 7)) << 3));
}

__global__ __launch_bounds__(256, 2)
void varlen_attn_mfma(const float* __restrict__ qkv, const int* __restrict__ cu,
                      float* __restrict__ out) {
  const int bh = blockIdx.x;
  const int b = bh >> 3, h = bh & 7;
  const int start = cu[b];
  const int len = cu[b + 1] - start;
  const int qb0 = blockIdx.y * QT;
  if (qb0 >= len) return;   // block-uniform exit, before any barrier

  __shared__ __align__(16) short Q_lds[QT * HD];       // 8 KB
  __shared__ __align__(16) short K_lds[KVB * HD];      // 8 KB, row-major [key][d]
  __shared__ __align__(16) short Vt_lds[HD * KVB];     // 8 KB, transposed [d][key]
  __shared__ __align__(16) short P_lds[4 * 16 * KVB];  // 8 KB, per-wave [16][64]

  const int t = threadIdx.x;
  const int w = t >> 6;        // wave 0..3
  const int lane = t & 63;
  const int li = lane & 15;
  const int g = lane >> 4;

  // ---- stage Q once (scaled by 1/sqrt(64)=0.125) ----
#pragma unroll
  for (int it = 0; it < 4; ++it) {
    const int row = it * 16 + (t >> 4);
    const int d0 = (t & 15) * 4;
    const int tok = start + min(qb0 + row, len - 1);
    const float4 f = *(const float4*)(qkv + (size_t)tok * TOKS + h * HD + d0);
    bf16x4 v;
    v[0] = f2bf(f.x * 0.125f); v[1] = f2bf(f.y * 0.125f);
    v[2] = f2bf(f.z * 0.125f); v[3] = f2bf(f.w * 0.125f);
    *(bf16x4*)&Q_lds[swz(row, row * HD + d0)] = v;
  }
  __syncthreads();

  // A-frag (16x32): lane holds row=li, k = g*8..g*8+7 (+32 for chunk 1)
  bf16x8 qf0, qf1;
  {
    const int qr = w * 16 + li;
    qf0 = *(const bf16x8*)&Q_lds[swz(qr, qr * HD + g * 8)];
    qf1 = *(const bf16x8*)&Q_lds[swz(qr, qr * HD + 32 + g * 8)];
  }

  f32x4 o[4];
#pragma unroll
  for (int i = 0; i < 4; ++i) o[i] = (f32x4){0.f, 0.f, 0.f, 0.f};
  f32x4 mrun = (f32x4){-1e30f, -1e30f, -1e30f, -1e30f};
  f32x4 sden = (f32x4){0.f, 0.f, 0.f, 0.f};

  for (int kv0 = 0; kv0 < len; kv0 += KVB) {
    __syncthreads();   // all waves done reading K/Vt of prev tile
    // ---- stage K (row-major) and V (transposed), both bf16+swizzled ----
#pragma unroll
    for (int it = 0; it < 4; ++it) {
      const int key = it * 16 + (t >> 4);
      const int d0 = (t & 15) * 4;
      const int tok = start + min(kv0 + key, len - 1);   // clamp: no OOB; masked later
      const float* base = qkv + (size_t)tok * TOKS + h * HD + d0;
      const float4 kf = *(const float4*)(base + 512);    // K component
      const float4 vf = *(const float4*)(base + 1024);   // V component
      bf16x4 k4;
      k4[0] = f2bf(kf.x); k4[1] = f2bf(kf.y); k4[2] = f2bf(kf.z); k4[3] = f2bf(kf.w);
      *(bf16x4*)&K_lds[swz(key, key * HD + d0)] = k4;
      const float vv[4] = {vf.x, vf.y, vf.z, vf.w};
#pragma unroll
      for (int dd = 0; dd < 4; ++dd) {
        const int vr = d0 + dd;
        Vt_lds[swz(vr, vr * KVB + key)] = f2bf(vv[dd]);
      }
    }
    __syncthreads();

    // ---- QK^T: sc[kt][reg] = S[q = 4g+reg][k-col = kt*16+li] ----
    f32x4 sc[4];
#pragma unroll
    for (int kt = 0; kt < 4; ++kt) {
      sc[kt] = (f32x4){0.f, 0.f, 0.f, 0.f};
      const int kr = kt * 16 + li;   // B-frag: col=li -> key row, k-dim = d
      const bf16x8 ka = *(const bf16x8*)&K_lds[swz(kr, kr * HD + g * 8)];
      const bf16x8 kb = *(const bf16x8*)&K_lds[swz(kr, kr * HD + 32 + g * 8)];
      sc[kt] = __builtin_amdgcn_mfma_f32_16x16x32_bf16(qf0, ka, sc[kt], 0, 0, 0);
      sc[kt] = __builtin_amdgcn_mfma_f32_16x16x32_bf16(qf1, kb, sc[kt], 0, 0, 0);
    }

    // mask invalid keys (tail of sequence / clamped duplicates)
#pragma unroll
    for (int kt = 0; kt < 4; ++kt)
      if (kv0 + kt * 16 + li >= len)
        sc[kt] = (f32x4){-1e9f, -1e9f, -1e9f, -1e9f};

    // ---- online softmax: rows live across the 16 lanes sharing g ----
    f32x4 mx = sc[0];
#pragma unroll
    for (int kt = 1; kt < 4; ++kt)
#pragma unroll
      for (int i = 0; i < 4; ++i) mx[i] = fmaxf(mx[i], sc[kt][i]);
#pragma unroll
    for (int msk = 1; msk < 16; msk <<= 1)
#pragma unroll
      for (int i = 0; i < 4; ++i) mx[i] = fmaxf(mx[i], __shfl_xor(mx[i], msk, 64));

    f32x4 mnew, cc;
#pragma unroll
    for (int i = 0; i < 4; ++i) {
      mnew[i] = fmaxf(mrun[i], mx[i]);
      cc[i] = __expf(mrun[i] - mnew[i]);
    }
    f32x4 p[4];
    f32x4 rs = (f32x4){0.f, 0.f, 0.f, 0.f};
#pragma unroll
    for (int kt = 0; kt < 4; ++kt)
#pragma unroll
      for (int i = 0; i < 4; ++i) {
        p[kt][i] = __expf(sc[kt][i] - mnew[i]);   // masked keys: exp(-1e9-m) = 0
        rs[i] += p[kt][i];
      }
#pragma unroll
    for (int msk = 1; msk < 16; msk <<= 1)
#pragma unroll
      for (int i = 0; i < 4; ++i) rs[i] += __shfl_xor(rs[i], msk, 64);
#pragma unroll
    for (int i = 0; i < 4; ++i) {
      sden[i] = sden[i] * cc[i] + rs[i];
      mrun[i] = mnew[i];
    }
#pragma unroll
    for (int dt = 0; dt < 4; ++dt)
#pragma unroll
      for (int i = 0; i < 4; ++i) o[dt][i] *= cc[i];

    // ---- write P (C-layout -> LDS), re-read as A-frags for PV ----
#pragma unroll
    for (int kt = 0; kt < 4; ++kt)
#pragma unroll
      for (int i = 0; i < 4; ++i) {
        const int r = g * 4 + i;
        P_lds[w * 1024 + swz(r, r * KVB + kt * 16 + li)] = f2bf(p[kt][i]);
      }
    __syncthreads();   // P visible (also orders Vt reads below vs next staging)

    // ---- PV: o[dt] += P(16x32) * V[k][d-tile dt] ----
#pragma unroll
    for (int c = 0; c < 2; ++c) {
      const bf16x8 pf =
          *(const bf16x8*)&P_lds[w * 1024 + swz(li, li * KVB + c * 32 + g * 8)];
#pragma unroll
      for (int dt = 0; dt < 4; ++dt) {
        const int vr = dt * 16 + li;   // B-frag: col=li -> d, k-dim = key
        const bf16x8 vfr =
            *(const bf16x8*)&Vt_lds[swz(vr, vr * KVB + c * 32 + g * 8)];
        o[dt] = __builtin_amdgcn_mfma_f32_16x16x32_bf16(pf, vfr, o[dt], 0, 0, 0);
      }
    }
  }

  // ---- epilogue: C-layout rows 4g+reg, cols dt*16+li ----
#pragma unroll
  for (int i = 0; i < 4; ++i) {
    const int grow = qb0 + w * 16 + g * 4 + i;
    if (grow < len) {
      const float inv = 1.f / sden[i];
      float* orow = out + (size_t)(start + grow) * OUTS + h * HD;
#pragma unroll
      for (int dt = 0; dt < 4; ++dt) orow[dt * 16 + li] = o[dt][i] * inv;
    }
  }
}

extern "C" void kernel_launch(void* const* d_in, const int* in_sizes, int n_in,
                              void* d_out, int out_size, void* d_ws, size_t ws_size,
                              hipStream_t stream) {
  const float* qkv = (const float*)d_in[0];
  const int* cu = (const int*)d_in[1];
  float* out = (float*)d_out;
  dim3 grid(64 * NH, MAXS / QT);   // (512, 8)
  varlen_attn_mfma<<<grid, 256, 0, stream>>>(qkv, cu, out);
}

// Round 4
// 81.191 us; speedup vs baseline: 12.4652x; 1.2072x over previous
//
#include <hip/hip_runtime.h>
#include <stdint.h>

#define NH 8
#define HD 64
#define MAXS 512
#define QT 128         // q rows per block; 32 per wave = 2 x 16-row A-frags
#define KVB 64
#define TOKS 1536      // 3*NH*HD floats per token
#define OUTS 512       // NH*HD floats per token

typedef __attribute__((ext_vector_type(8))) short bf16x8;
typedef __attribute__((ext_vector_type(4))) short bf16x4;
typedef __attribute__((ext_vector_type(4))) float f32x4;

__device__ __forceinline__ short f2bf(float f) {
  uint32_t u = __float_as_uint(f);
  u += 0x7fffu + ((u >> 16) & 1u);
  return (short)(u >> 16);
}
// XOR swizzle on short-index within a [R][64] bf16 tile (row stride 128 B)
__device__ __forceinline__ int swz(int row, int idx) {
  return idx ^ ((((row & 7) ^ ((row >> 3) & 7)) << 3));
}

__global__ __launch_bounds__(256, 2)
void varlen_attn_mfma2(const float* __restrict__ qkv, const int* __restrict__ cu,
                       float* __restrict__ out) {
  const int bh = blockIdx.x;
  const int b = bh >> 3, h = bh & 7;
  const int start = cu[b];
  const int len = cu[b + 1] - start;
  const int qb0 = blockIdx.y * QT;
  if (qb0 >= len) return;   // block-uniform exit before any barrier

  __shared__ __align__(16) short Kb[2][KVB * HD];    // 16 KB (dbuf)
  __shared__ __align__(16) short Vtb[2][HD * KVB];   // 16 KB (dbuf, transposed)
  __shared__ __align__(16) short P_lds[4][16 * KVB]; // 8 KB, per-wave

  const int t = threadIdx.x;
  const int w = t >> 6, lane = t & 63, li = lane & 15, g = lane >> 4;

  // ---- Q straight to registers (scaled by 0.125) ----
  bf16x8 qa[2][2];   // [qfrag][k-chunk]
#pragma unroll
  for (int qf = 0; qf < 2; ++qf) {
    const int qrow = qb0 + w * 32 + qf * 16 + li;
    const float* qp = qkv + (size_t)(start + min(qrow, len - 1)) * TOKS + h * HD;
#pragma unroll
    for (int c = 0; c < 2; ++c) {
      const float4 f0 = *(const float4*)(qp + c * 32 + g * 8);
      const float4 f1 = *(const float4*)(qp + c * 32 + g * 8 + 4);
      bf16x8 v;
      v[0] = f2bf(f0.x * 0.125f); v[1] = f2bf(f0.y * 0.125f);
      v[2] = f2bf(f0.z * 0.125f); v[3] = f2bf(f0.w * 0.125f);
      v[4] = f2bf(f1.x * 0.125f); v[5] = f2bf(f1.y * 0.125f);
      v[6] = f2bf(f1.z * 0.125f); v[7] = f2bf(f1.w * 0.125f);
      qa[qf][c] = v;
    }
  }

  f32x4 o[2][4];
  f32x4 mrun[2], sden[2];
#pragma unroll
  for (int qf = 0; qf < 2; ++qf) {
    mrun[qf] = (f32x4){-1e30f, -1e30f, -1e30f, -1e30f};
    sden[qf] = (f32x4){0.f, 0.f, 0.f, 0.f};
#pragma unroll
    for (int dt = 0; dt < 4; ++dt) o[qf][dt] = (f32x4){0.f, 0.f, 0.f, 0.f};
  }

  const int nt = (len + KVB - 1) / KVB;
  const int skey = t >> 2;        // staging: key 0..63 (4 threads/key)
  const int sd0 = (t & 3) * 16;   // staging: d-range start

  // ---- prologue: load tile 0 to regs, write LDS buf 0 ----
  float4 kreg[4], vreg[4];
  {
    const float* base = qkv + (size_t)(start + min(skey, len - 1)) * TOKS + h * HD + sd0;
#pragma unroll
    for (int j = 0; j < 4; ++j) {
      kreg[j] = *(const float4*)(base + 512 + j * 4);
      vreg[j] = *(const float4*)(base + 1024 + j * 4);
    }
  }
#pragma unroll
  for (int j = 0; j < 4; ++j) {
    bf16x4 k4;
    k4[0] = f2bf(kreg[j].x); k4[1] = f2bf(kreg[j].y);
    k4[2] = f2bf(kreg[j].z); k4[3] = f2bf(kreg[j].w);
    *(bf16x4*)&Kb[0][swz(skey, skey * HD + sd0 + j * 4)] = k4;
    const float vv[4] = {vreg[j].x, vreg[j].y, vreg[j].z, vreg[j].w};
#pragma unroll
    for (int dd = 0; dd < 4; ++dd) {
      const int vr = sd0 + j * 4 + dd;
      Vtb[0][swz(vr, vr * KVB + skey)] = f2bf(vv[dd]);
    }
  }
  __syncthreads();

  for (int tt = 0; tt < nt; ++tt) {
    const int cur = tt & 1;
    const int kv0 = tt * KVB;
    const bool pf = (tt + 1 < nt);
    // ---- issue next tile's global loads (consumed at bottom of body) ----
    if (pf) {
      const float* base =
          qkv + (size_t)(start + min(kv0 + KVB + skey, len - 1)) * TOKS + h * HD + sd0;
#pragma unroll
      for (int j = 0; j < 4; ++j) {
        kreg[j] = *(const float4*)(base + 512 + j * 4);
        vreg[j] = *(const float4*)(base + 1024 + j * 4);
      }
    }

#pragma unroll
    for (int qf = 0; qf < 2; ++qf) {
      // ---- QK^T: sc[kt][i] = S[q=4g+i][key=kt*16+li] ----
      f32x4 sc[4];
#pragma unroll
      for (int kt = 0; kt < 4; ++kt) {
        sc[kt] = (f32x4){0.f, 0.f, 0.f, 0.f};
        const int kr = kt * 16 + li;
#pragma unroll
        for (int c = 0; c < 2; ++c) {
          const bf16x8 ka = *(const bf16x8*)&Kb[cur][swz(kr, kr * HD + c * 32 + g * 8)];
          sc[kt] = __builtin_amdgcn_mfma_f32_16x16x32_bf16(qa[qf][c], ka, sc[kt], 0, 0, 0);
        }
      }
#pragma unroll
      for (int kt = 0; kt < 4; ++kt)
        if (kv0 + kt * 16 + li >= len) sc[kt] = (f32x4){-1e9f, -1e9f, -1e9f, -1e9f};

      // ---- online softmax: row's keys live across the 16 lanes sharing g ----
      f32x4 mx = sc[0];
#pragma unroll
      for (int kt = 1; kt < 4; ++kt)
#pragma unroll
        for (int i = 0; i < 4; ++i) mx[i] = fmaxf(mx[i], sc[kt][i]);
#pragma unroll
      for (int msk = 1; msk < 16; msk <<= 1)
#pragma unroll
        for (int i = 0; i < 4; ++i) mx[i] = fmaxf(mx[i], __shfl_xor(mx[i], msk, 64));

      f32x4 mnew, cc;
#pragma unroll
      for (int i = 0; i < 4; ++i) {
        mnew[i] = fmaxf(mrun[qf][i], mx[i]);
        cc[i] = __expf(mrun[qf][i] - mnew[i]);
        mrun[qf][i] = mnew[i];
      }
      f32x4 p[4], rs = (f32x4){0.f, 0.f, 0.f, 0.f};
#pragma unroll
      for (int kt = 0; kt < 4; ++kt)
#pragma unroll
        for (int i = 0; i < 4; ++i) {
          p[kt][i] = __expf(sc[kt][i] - mnew[i]);   // masked: exp(-1e9-m)=0
          rs[i] += p[kt][i];
        }
#pragma unroll
      for (int msk = 1; msk < 16; msk <<= 1)
#pragma unroll
        for (int i = 0; i < 4; ++i) rs[i] += __shfl_xor(rs[i], msk, 64);
#pragma unroll
      for (int i = 0; i < 4; ++i) sden[qf][i] = sden[qf][i] * cc[i] + rs[i];
#pragma unroll
      for (int dt = 0; dt < 4; ++dt)
#pragma unroll
        for (int i = 0; i < 4; ++i) o[qf][dt][i] *= cc[i];

      // ---- P relayout via per-wave LDS (no barrier: same-wave RAW) ----
#pragma unroll
      for (int kt = 0; kt < 4; ++kt)
#pragma unroll
        for (int i = 0; i < 4; ++i) {
          const int r = g * 4 + i;
          P_lds[w][swz(r, r * KVB + kt * 16 + li)] = f2bf(p[kt][i]);
        }

      // ---- PV: o[qf][dt] += P(16x32) x V-tile ----
#pragma unroll
      for (int c = 0; c < 2; ++c) {
        const bf16x8 pfr = *(const bf16x8*)&P_lds[w][swz(li, li * KVB + c * 32 + g * 8)];
#pragma unroll
        for (int dt = 0; dt < 4; ++dt) {
          const int vr = dt * 16 + li;
          const bf16x8 vfr = *(const bf16x8*)&Vtb[cur][swz(vr, vr * KVB + c * 32 + g * 8)];
          o[qf][dt] = __builtin_amdgcn_mfma_f32_16x16x32_bf16(pfr, vfr, o[qf][dt], 0, 0, 0);
        }
      }
    }

    // ---- drain prefetched regs into the other LDS buffer ----
    if (pf) {
      const int nb = cur ^ 1;
#pragma unroll
      for (int j = 0; j < 4; ++j) {
        bf16x4 k4;
        k4[0] = f2bf(kreg[j].x); k4[1] = f2bf(kreg[j].y);
        k4[2] = f2bf(kreg[j].z); k4[3] = f2bf(kreg[j].w);
        *(bf16x4*)&Kb[nb][swz(skey, skey * HD + sd0 + j * 4)] = k4;
        const float vv[4] = {vreg[j].x, vreg[j].y, vreg[j].z, vreg[j].w};
#pragma unroll
        for (int dd = 0; dd < 4; ++dd) {
          const int vr = sd0 + j * 4 + dd;
          Vtb[nb][swz(vr, vr * KVB + skey)] = f2bf(vv[dd]);
        }
      }
    }
    __syncthreads();   // the ONE barrier per tile
  }

  // ---- epilogue ----
#pragma unroll
  for (int qf = 0; qf < 2; ++qf)
#pragma unroll
    for (int i = 0; i < 4; ++i) {
      const int grow = qb0 + w * 32 + qf * 16 + g * 4 + i;
      if (grow < len) {
        const float inv = 1.f / sden[qf][i];
        float* orow = out + (size_t)(start + grow) * OUTS + h * HD;
#pragma unroll
        for (int dt = 0; dt < 4; ++dt) orow[dt * 16 + li] = o[qf][dt][i] * inv;
      }
    }
}

extern "C" void kernel_launch(void* const* d_in, const int* in_sizes, int n_in,
                              void* d_out, int out_size, void* d_ws, size_t ws_size,
                              hipStream_t stream) {
  const float* qkv = (const float*)d_in[0];
  const int* cu = (const int*)d_in[1];
  float* out = (float*)d_out;
  dim3 grid(64 * NH, (MAXS + QT - 1) / QT);   // (512, 4)
  varlen_attn_mfma2<<<grid, 256, 0, stream>>>(qkv, cu, out);
}

// Round 5
// 49.117 us; speedup vs baseline: 20.6048x; 1.6530x over previous
//
#include <hip/hip_runtime.h>
#include <stdint.h>

#define NH 8
#define HD 64
#define MAXS 512
#define QT 128         // 4 waves x 32 q-rows
#define KVB 64
#define TOKS 1536      // 3*NH*HD floats per token
#define OUTS 512       // NH*HD floats per token

typedef __attribute__((ext_vector_type(8))) short bf16x8;
typedef __attribute__((ext_vector_type(16))) float f32x16;

// two f32 -> one u32 holding two bf16 (RNE), low short = first arg
__device__ __forceinline__ unsigned cvt_pk(float lo, float hi) {
  unsigned r;
  asm("v_cvt_pk_bf16_f32 %0, %1, %2" : "=v"(r) : "v"(lo), "v"(hi));
  return r;
}
// XOR swizzle on short-index within a [R][64] bf16 tile (row stride 128 B)
__device__ __forceinline__ int swz(int row, int idx) {
  return idx ^ ((((row & 7) ^ ((row >> 3) & 7)) << 3));
}
// cross-half (lane vs lane^32) reduce via v_permlane32_swap_b32 (VALU-only)
__device__ __forceinline__ float xmax32(float x) {
  float y;
  asm volatile("v_mov_b32 %0, %1" : "=v"(y) : "v"(x));
  asm volatile("v_permlane32_swap_b32 %0, %1" : "+v"(x), "+v"(y));
  return fmaxf(x, y);
}
__device__ __forceinline__ float xadd32(float x) {
  float y;
  asm volatile("v_mov_b32 %0, %1" : "=v"(y) : "v"(x));
  asm volatile("v_permlane32_swap_b32 %0, %1" : "+v"(x), "+v"(y));
  return x + y;
}
__device__ __forceinline__ void plswap(unsigned &a, unsigned &b) {
  asm volatile("v_permlane32_swap_b32 %0, %1" : "+v"(a), "+v"(b));
}

__global__ __launch_bounds__(256, 3)
void varlen_attn_mfma3(const float* __restrict__ qkv, const int* __restrict__ cu,
                       float* __restrict__ out) {
  const int bh = blockIdx.x;
  const int b = bh >> 3, h = bh & 7;
  const int start = cu[b];
  const int len = cu[b + 1] - start;
  const int qb0 = blockIdx.y * QT;
  if (qb0 >= len) return;   // block-uniform exit before any barrier

  __shared__ __align__(16) short Kb[2][KVB * HD];    // 16 KB dbuf, [key][d]
  __shared__ __align__(16) short Vtb[2][HD * KVB];   // 16 KB dbuf, [d][key]

  const int t = threadIdx.x;
  const int w = t >> 6, lane = t & 63;
  const int l31 = lane & 31, hi = lane >> 5;

  // ---- Q B-frags (col q = l31, k-elem d = dc*16 + hi*8 + j), scaled 0.125 ----
  const int qrow = qb0 + w * 32 + l31;
  bf16x8 qbf[4];
  {
    const float* qp = qkv + (size_t)(start + min(qrow, len - 1)) * TOKS + h * HD;
#pragma unroll
    for (int dc = 0; dc < 4; ++dc) {
      const float4 f0 = *(const float4*)(qp + dc * 16 + hi * 8);
      const float4 f1 = *(const float4*)(qp + dc * 16 + hi * 8 + 4);
      union { unsigned u[4]; bf16x8 v; } qq;
      qq.u[0] = cvt_pk(f0.x * 0.125f, f0.y * 0.125f);
      qq.u[1] = cvt_pk(f0.z * 0.125f, f0.w * 0.125f);
      qq.u[2] = cvt_pk(f1.x * 0.125f, f1.y * 0.125f);
      qq.u[3] = cvt_pk(f1.z * 0.125f, f1.w * 0.125f);
      qbf[dc] = qq.v;
    }
  }

  f32x16 o0, o1;   // O^T acc: d-groups 0..31 / 32..63, col q = l31
#pragma unroll
  for (int i = 0; i < 16; ++i) { o0[i] = 0.f; o1[i] = 0.f; }
  float mrun = -1e30f, sden = 0.f;

  const int nt = (len + KVB - 1) / KVB;
  const int kp = t >> 3;          // key pair index 0..31 -> keys 2kp, 2kp+1
  const int d0s = (t & 7) * 8;    // 8-wide d segment

  float4 kr0, kr1, kr2, kr3, vr0, vr1, vr2, vr3;
  auto issue = [&](int kv) {
    const float* b0 = qkv + (size_t)(start + min(kv + 2 * kp, len - 1)) * TOKS + h * HD + d0s;
    const float* b1 = qkv + (size_t)(start + min(kv + 2 * kp + 1, len - 1)) * TOKS + h * HD + d0s;
    kr0 = *(const float4*)(b0 + 512);  kr1 = *(const float4*)(b0 + 516);
    kr2 = *(const float4*)(b1 + 512);  kr3 = *(const float4*)(b1 + 516);
    vr0 = *(const float4*)(b0 + 1024); vr1 = *(const float4*)(b0 + 1028);
    vr2 = *(const float4*)(b1 + 1024); vr3 = *(const float4*)(b1 + 1028);
  };
  auto drain = [&](int nb) {
    short* Kd = &Kb[nb][0];
    short* Vd = &Vtb[nb][0];
    union { unsigned u[4]; bf16x8 v; } kk;
    kk.u[0] = cvt_pk(kr0.x, kr0.y); kk.u[1] = cvt_pk(kr0.z, kr0.w);
    kk.u[2] = cvt_pk(kr1.x, kr1.y); kk.u[3] = cvt_pk(kr1.z, kr1.w);
    *(bf16x8*)&Kd[swz(2 * kp, (2 * kp) * HD + d0s)] = kk.v;
    kk.u[0] = cvt_pk(kr2.x, kr2.y); kk.u[1] = cvt_pk(kr2.z, kr2.w);
    kk.u[2] = cvt_pk(kr3.x, kr3.y); kk.u[3] = cvt_pk(kr3.z, kr3.w);
    *(bf16x8*)&Kd[swz(2 * kp + 1, (2 * kp + 1) * HD + d0s)] = kk.v;
    // V transpose: word = (bf16 V[2kp][d], bf16 V[2kp+1][d]) -> Vt[d][2kp..2kp+1]
    *(unsigned*)&Vd[swz(d0s + 0, (d0s + 0) * KVB + 2 * kp)] = cvt_pk(vr0.x, vr2.x);
    *(unsigned*)&Vd[swz(d0s + 1, (d0s + 1) * KVB + 2 * kp)] = cvt_pk(vr0.y, vr2.y);
    *(unsigned*)&Vd[swz(d0s + 2, (d0s + 2) * KVB + 2 * kp)] = cvt_pk(vr0.z, vr2.z);
    *(unsigned*)&Vd[swz(d0s + 3, (d0s + 3) * KVB + 2 * kp)] = cvt_pk(vr0.w, vr2.w);
    *(unsigned*)&Vd[swz(d0s + 4, (d0s + 4) * KVB + 2 * kp)] = cvt_pk(vr1.x, vr3.x);
    *(unsigned*)&Vd[swz(d0s + 5, (d0s + 5) * KVB + 2 * kp)] = cvt_pk(vr1.y, vr3.y);
    *(unsigned*)&Vd[swz(d0s + 6, (d0s + 6) * KVB + 2 * kp)] = cvt_pk(vr1.z, vr3.z);
    *(unsigned*)&Vd[swz(d0s + 7, (d0s + 7) * KVB + 2 * kp)] = cvt_pk(vr1.w, vr3.w);
  };

  issue(0);
  drain(0);
  __syncthreads();

  for (int tt = 0; tt < nt; ++tt) {
    const int cur = tt & 1;
    const int kv0 = tt * KVB;
    const bool pfb = (tt + 1 < nt);
    if (pfb) issue(kv0 + KVB);

    const short* Kc = &Kb[cur][0];
    const short* Vc = &Vtb[cur][0];

    // ---- S^T = K x Q (swapped): C col = q = l31, row = key offset ----
    f32x16 s0, s1;
#pragma unroll
    for (int i = 0; i < 16; ++i) { s0[i] = 0.f; s1[i] = 0.f; }
#pragma unroll
    for (int dc = 0; dc < 4; ++dc) {
      const bf16x8 k0 = *(const bf16x8*)&Kc[swz(l31, l31 * HD + dc * 16 + hi * 8)];
      const bf16x8 k1 = *(const bf16x8*)&Kc[swz(32 + l31, (32 + l31) * HD + dc * 16 + hi * 8)];
      s0 = __builtin_amdgcn_mfma_f32_32x32x16_bf16(k0, qbf[dc], s0, 0, 0, 0);
      s1 = __builtin_amdgcn_mfma_f32_32x32x16_bf16(k1, qbf[dc], s1, 0, 0, 0);
    }

    // ---- mask tail keys (only the last tile can have any) ----
    if (kv0 + KVB > len) {
      const int kb = kv0 + 4 * hi;
#pragma unroll
      for (int r = 0; r < 16; ++r) {
        const int ko = (r & 3) + 8 * (r >> 2);
        if (kb + ko >= len) s0[r] = -1e9f;
        if (kb + 32 + ko >= len) s1[r] = -1e9f;
      }
    }

    // ---- lane-local online softmax (one permlane swap per reduce) ----
    float mx = s0[0];
#pragma unroll
    for (int r = 1; r < 16; ++r) mx = fmaxf(mx, s0[r]);
#pragma unroll
    for (int r = 0; r < 16; ++r) mx = fmaxf(mx, s1[r]);
    mx = xmax32(mx);
    const float mnew = fmaxf(mrun, mx);
    const float cc = __expf(mrun - mnew);
    mrun = mnew;
    float rs = 0.f;
#pragma unroll
    for (int r = 0; r < 16; ++r) {
      s0[r] = __expf(s0[r] - mnew); rs += s0[r];
      s1[r] = __expf(s1[r] - mnew); rs += s1[r];
    }
    rs = xadd32(rs);
    sden = sden * cc + rs;
#pragma unroll
    for (int i = 0; i < 16; ++i) { o0[i] *= cc; o1[i] *= cc; }

    if (pfb) drain(cur ^ 1);   // buf cur^1 free since last barrier; overlaps PV

    // ---- PV: O^T += V^T x P^T; P-frag built in-register per 16-key chunk ----
#pragma unroll
    for (int kc = 0; kc < 4; ++kc) {
      unsigned a01, a23, a45, a67;
      if (kc == 0)      { a01=cvt_pk(s0[0],s0[1]);   a23=cvt_pk(s0[2],s0[3]);
                          a45=cvt_pk(s0[4],s0[5]);   a67=cvt_pk(s0[6],s0[7]); }
      else if (kc == 1) { a01=cvt_pk(s0[8],s0[9]);   a23=cvt_pk(s0[10],s0[11]);
                          a45=cvt_pk(s0[12],s0[13]); a67=cvt_pk(s0[14],s0[15]); }
      else if (kc == 2) { a01=cvt_pk(s1[0],s1[1]);   a23=cvt_pk(s1[2],s1[3]);
                          a45=cvt_pk(s1[4],s1[5]);   a67=cvt_pk(s1[6],s1[7]); }
      else              { a01=cvt_pk(s1[8],s1[9]);   a23=cvt_pk(s1[10],s1[11]);
                          a45=cvt_pk(s1[12],s1[13]); a67=cvt_pk(s1[14],s1[15]); }
      plswap(a01, a45);   // -> frag words w0, w2 (keys hi*8+{0,1} / {4,5})
      plswap(a23, a67);   // -> frag words w1, w3 (keys hi*8+{2,3} / {6,7})
      union { unsigned u[4]; bf16x8 v; } pf;
      pf.u[0] = a01; pf.u[1] = a23; pf.u[2] = a45; pf.u[3] = a67;
      const bf16x8 v0 = *(const bf16x8*)&Vc[swz(l31, l31 * KVB + kc * 16 + hi * 8)];
      const bf16x8 v1 = *(const bf16x8*)&Vc[swz(32 + l31, (32 + l31) * KVB + kc * 16 + hi * 8)];
      o0 = __builtin_amdgcn_mfma_f32_32x32x16_bf16(v0, pf.v, o0, 0, 0, 0);
      o1 = __builtin_amdgcn_mfma_f32_32x32x16_bf16(v1, pf.v, o1, 0, 0, 0);
    }
    __syncthreads();   // one barrier per tile
  }

  // ---- epilogue: O^T reg r -> d = (r&3) + 8*(r>>2) + 4*hi (+32 for o1) ----
  if (qrow < len) {
    const float inv = 1.f / sden;
    float* orow = out + (size_t)(start + qrow) * OUTS + h * HD;
#pragma unroll
    for (int q4 = 0; q4 < 4; ++q4) {
      float4 t0, t1;
      t0.x = o0[q4*4+0]*inv; t0.y = o0[q4*4+1]*inv;
      t0.z = o0[q4*4+2]*inv; t0.w = o0[q4*4+3]*inv;
      t1.x = o1[q4*4+0]*inv; t1.y = o1[q4*4+1]*inv;
      t1.z = o1[q4*4+2]*inv; t1.w = o1[q4*4+3]*inv;
      *(float4*)(orow + 8*q4 + 4*hi) = t0;
      *(float4*)(orow + 32 + 8*q4 + 4*hi) = t1;
    }
  }
}

extern "C" void kernel_launch(void* const* d_in, const int* in_sizes, int n_in,
                              void* d_out, int out_size, void* d_ws, size_t ws_size,
                              hipStream_t stream) {
  const float* qkv = (const float*)d_in[0];
  const int* cu = (const int*)d_in[1];
  float* out = (float*)d_out;
  dim3 grid(64 * NH, (MAXS + QT - 1) / QT);   // (512, 4)
  varlen_attn_mfma3<<<grid, 256, 0, stream>>>(qkv, cu, out);
}